// Round 2
// baseline (4319.798 us; speedup 1.0000x reference)
//
#include <hip/hip_runtime.h>
#include <cstdint>
#include <cstddef>

// RecurrentDecoder: 128 sequential GRU steps fused via x_t = h_t @ W_dec^T
// => gates = h @ W_eff^T (4096 gate cols + 256 decode cols), one GEMM/step.
// Round 8 (= Round 7 hardened; R7 never executed - GPU capacity):
//  - persistent cooperative kernel (1 launch, 256 blocks = 1/CU)
//  - per-mt device-scope barriers between steps (only same-mt blocks exchange h)
//  - NBUF=3 DMA pipeline, counted s_waitcnt vmcnt(N) + raw s_barrier
//  - fp32 hold carried in registers across steps (h32 buffers unused in coop path)
//  - NEW: s_setprio around MFMA cluster (T5); s_sleep in barrier spin
//  - NEW: if hipLaunchCooperativeKernel is rejected at enqueue, fall back to the
//    proven multi-launch step_kernel path (baseline 2989us) instead of failing.
// 256 blocks = 8 mt x 32 cb; block tile [128 x 144], 4 waves (2x2).

#define HD 1024
#define OD 256
#define TS 128
#define NBUF 3
#define ABUF 16384
#define BBUF 18432

typedef _Float16 f16x8 __attribute__((ext_vector_type(8)));
typedef float f32x4 __attribute__((ext_vector_type(4)));

__device__ __forceinline__ void gl_lds16(const void* g, void* l) {
  auto gp = reinterpret_cast<const __attribute__((address_space(1))) unsigned int*>(
      reinterpret_cast<uintptr_t>(g));
  auto lp = reinterpret_cast<__attribute__((address_space(3))) unsigned int*>(
      reinterpret_cast<uintptr_t>(l));
  __builtin_amdgcn_global_load_lds(gp, lp, 16, 0, 0);
}

// ---------------- prep: build W_ws [32 cb][144 rows][1024 k] fp16 ----------------
__global__ __launch_bounds__(256) void prep_w(
    const float* __restrict__ Wih,   // [3072][256]
    const float* __restrict__ Whh,   // [3072][1024]
    const float* __restrict__ Wdec,  // [256][1024]
    _Float16* __restrict__ Wws)      // [32][144][1024]
{
  int blk = blockIdx.x, tid = threadIdx.x;
  int k0 = tid * 4;
  if (blk < 768) {                      // dot blocks: rows rr<96 (s in 0..2), 4 rows each
    int cbv[4], rrv[4], jg[4], jh[4];
    #pragma unroll
    for (int rsel = 0; rsel < 4; ++rsel) {
      int dj = blk * 4 + rsel;
      int cb = dj / 96, rr = dj % 96;
      int s = rr >> 5, wcol = (rr >> 4) & 1, p = rr & 15;
      int j = cb * 32 + wcol * 16 + p;
      cbv[rsel] = cb; rrv[rsel] = rr;
      jg[rsel] = s * 1024 + j;
      jh[rsel] = (s == 0) ? j : (s == 1 ? 1024 + j : -1);
    }
    float acc[4][4];
    #pragma unroll
    for (int a = 0; a < 4; ++a) { acc[a][0]=0.f; acc[a][1]=0.f; acc[a][2]=0.f; acc[a][3]=0.f; }
    for (int q = 0; q < 256; ++q) {
      float4 wd = *(const float4*)(Wdec + (size_t)q * 1024 + k0);
      #pragma unroll
      for (int a = 0; a < 4; ++a) {
        float w = Wih[(size_t)jg[a] * 256 + q];
        acc[a][0] += w * wd.x; acc[a][1] += w * wd.y;
        acc[a][2] += w * wd.z; acc[a][3] += w * wd.w;
      }
    }
    #pragma unroll
    for (int a = 0; a < 4; ++a) {
      if (jh[a] >= 0) {
        const float* wh = Whh + (size_t)jh[a] * 1024 + k0;
        acc[a][0] += wh[0]; acc[a][1] += wh[1];
        acc[a][2] += wh[2]; acc[a][3] += wh[3];
      }
      _Float16* dst = Wws + ((size_t)cbv[a] * 144 + rrv[a]) * 1024 + k0;
      dst[0] = (_Float16)acc[a][0]; dst[1] = (_Float16)acc[a][1];
      dst[2] = (_Float16)acc[a][2]; dst[3] = (_Float16)acc[a][3];
    }
  } else {                              // copy blocks: rows rr in 96..143
    #pragma unroll
    for (int rsel = 0; rsel < 4; ++rsel) {
      int cr = (blk - 768) * 4 + rsel;
      int cb = cr / 48, rr = 96 + cr % 48;
      _Float16* dst = Wws + ((size_t)cb * 144 + rr) * 1024 + k0;
      if (rr < 128) {                   // s=3: Whh[2048+j]
        int j = cb * 32 + ((rr >> 4) & 1) * 16 + (rr & 15);
        const float* src = Whh + (size_t)(2048 + j) * 1024 + k0;
        dst[0] = (_Float16)src[0]; dst[1] = (_Float16)src[1];
        dst[2] = (_Float16)src[2]; dst[3] = (_Float16)src[3];
      } else if (rr < 136) {
        const float* src = Wdec + (size_t)(cb * 8 + rr - 128) * 1024 + k0;
        dst[0] = (_Float16)src[0]; dst[1] = (_Float16)src[1];
        dst[2] = (_Float16)src[2]; dst[3] = (_Float16)src[3];
      } else {
        dst[0] = (_Float16)0.f; dst[1] = (_Float16)0.f;
        dst[2] = (_Float16)0.f; dst[3] = (_Float16)0.f;
      }
    }
  }
}

__global__ __launch_bounds__(256) void prep_bias(
    const float* __restrict__ Wih,
    const float* __restrict__ bih, const float* __restrict__ bhh,
    const float* __restrict__ bdec_in,
    float* __restrict__ br, float* __restrict__ bz, float* __restrict__ bin_,
    float* __restrict__ bhn, float* __restrict__ bdec,
    unsigned int* __restrict__ ctr)
{
  int j = blockIdx.x * 256 + threadIdx.x;   // grid 4 -> j < 1024
  if (blockIdx.x == 0) ctr[threadIdx.x] = 0u;   // reset per-mt barrier counters
  float bc0 = 0.f, bc1 = 0.f, bc2 = 0.f;
  for (int q = 0; q < 256; ++q) {
    float bd = bdec_in[q];
    bc0 += Wih[(size_t)j * 256 + q] * bd;
    bc1 += Wih[(size_t)(1024 + j) * 256 + q] * bd;
    bc2 += Wih[(size_t)(2048 + j) * 256 + q] * bd;
  }
  br[j]  = bih[j]        + bhh[j]        + bc0;
  bz[j]  = bih[1024 + j] + bhh[1024 + j] + bc1;
  bin_[j]= bih[2048 + j] + bc2;
  bhn[j] = bhh[2048 + j];
  if (j < 256) bdec[j] = bdec_in[j];
}

__global__ __launch_bounds__(256) void prep_h(
    const float* __restrict__ h0, _Float16* __restrict__ h16)
{
  int i = blockIdx.x * 256 + threadIdx.x;
  h16[i] = (_Float16)h0[i];
}

// ---------------- persistent fused kernel (cooperative) ----------------
// grid 256 = mt(8)*32 + cb(32); 256 thr = 4 waves (2x2 over [128x128] gates).
// LDS: 3 A bufs (16384 B) then 3 B bufs (18432 B). Per buffer: [row][8 kgroups
// of 16B], row stride 128 B; kgroup XOR-swizzled by (row&7), folded into the
// DMA's per-lane GLOBAL address so LDS destinations stay lane-linear.
// K-loop: counted vmcnt (steady state 2 sets in flight; per-wave set size
// L = 9 (waves 0,1) / 8 (waves 2,3)); raw s_barrier, never vmcnt(0) mid-loop.
__global__ __launch_bounds__(256, 1) void fused_gru(
    const _Float16* __restrict__ Wws,
    const float* __restrict__ br, const float* __restrict__ bz,
    const float* __restrict__ bin_, const float* __restrict__ bhn,
    const float* __restrict__ bdec,
    const float* __restrict__ h0,
    _Float16* __restrict__ h16A, _Float16* __restrict__ h16B,
    float* __restrict__ out,
    unsigned int* __restrict__ ctr)
{
  __shared__ __align__(16) char lds[NBUF * (ABUF + BBUF)];   // 104448 B

  const int tid = threadIdx.x;
  const int wave = tid >> 6, lane = tid & 63;
  const int mt = blockIdx.x >> 5, cb = blockIdx.x & 31;
  const int wr = wave >> 1, wc = wave & 1;
  const int col16 = lane & 15, quad = lane >> 4;

  const _Float16* __restrict__ slab = Wws + (size_t)cb * (144 * 1024);

  // DMA chunk geometry: chunk m (16 B) covers row r=m>>3, lds-kgroup c=m&7;
  // global kgroup g = c ^ (r&7) (swizzle). Wave w, issue j covers chunks
  // (w*4+j)*64 + lane. Extra B chunks 1024+tid (tid<128) cover rows 128..143.
  int offs[4];
  #pragma unroll
  for (int jj = 0; jj < 4; ++jj) {
    int m = (wave * 4 + jj) * 64 + lane;
    int r = m >> 3, c = m & 7, g = c ^ (r & 7);
    offs[jj] = r * 1024 + g * 8;       // element (half) offset
  }
  int offE;
  { int m = 1024 + tid; int r = m >> 3, c = m & 7, g = c ^ (r & 7);
    offE = r * 1024 + g * 8; }         // valid when tid < 128

  const int swz = (quad ^ (col16 & 7)) << 4;   // ds_read swizzled col base; K-hi = ^64 B

  // loop-invariant epilogue constants (loaded once)
  const int j = cb * 32 + wc * 16 + col16;     // gate col 0..1023
  const float vbr = br[j], vbz = bz[j], vbi = bin_[j], vbh = bhn[j];
  const float vb = bdec[cb * 8 + (col16 & 7)]; // used only when col16 < 8

  // fp32 hold carried in registers across all 128 steps (C/D layout:
  // n = lane&15, m = quad*4 + reg). Seeded from h0.
  float hold[4][4];
  #pragma unroll
  for (int fm = 0; fm < 4; ++fm) {
    const int mbase = mt * 128 + 64 * wr + 16 * fm + quad * 4;
    #pragma unroll
    for (int ri = 0; ri < 4; ++ri)
      hold[fm][ri] = h0[(size_t)(mbase + ri) * 1024 + j];
  }
  // drain preloads so in-loop vmcnt accounting is exact
  asm volatile("s_waitcnt vmcnt(0)" ::: "memory");

  const f32x4 fzero = {0.f, 0.f, 0.f, 0.f};

  #pragma unroll 1
  for (int t = 0; t <= TS; ++t) {      // t=TS: decode-only pass for out[:,127,:]
    const _Float16* __restrict__ Abase =
        ((t & 1) ? h16B : h16A) + (size_t)mt * (128 * 1024);
    _Float16* __restrict__ o16 = (t & 1) ? h16A : h16B;

    f32x4 accG[4][4]; f32x4 accD[2];
    #pragma unroll
    for (int i = 0; i < 4; ++i)
      #pragma unroll
      for (int jj = 0; jj < 4; ++jj) accG[i][jj] = fzero;
    accD[0] = fzero; accD[1] = fzero;

    auto issue_dma = [&](int bsel, int kc) {
      char* Ab = lds + bsel * ABUF;
      char* Bb = lds + NBUF * ABUF + bsel * BBUF;
      #pragma unroll
      for (int jj = 0; jj < 4; ++jj) {
        gl_lds16(Abase + offs[jj] + kc, Ab + (wave * 4 + jj) * 1024);
        gl_lds16(slab  + offs[jj] + kc, Bb + (wave * 4 + jj) * 1024);
      }
      if (wave < 2)
        gl_lds16(slab + offE + kc, Bb + 16384 + wave * 1024);
    };

    // prologue: 3 K-sets in flight
    issue_dma(0, 0);
    issue_dma(1, 64);
    issue_dma(2, 128);

    int cur = 0;
    #pragma unroll 1
    for (int ki = 0; ki < 16; ++ki) {
      // counted wait: need set ki complete; allow 2 newer sets in flight.
      // Sets issued: 3 + min(ki,13). ki<=13 -> wait 2L; ki==14 -> L; ki==15 -> 0.
      __builtin_amdgcn_sched_barrier(0);
      if (ki < 14) {
        if (wave < 2) asm volatile("s_waitcnt vmcnt(18)" ::: "memory");
        else          asm volatile("s_waitcnt vmcnt(16)" ::: "memory");
      } else if (ki == 14) {
        if (wave < 2) asm volatile("s_waitcnt vmcnt(9)" ::: "memory");
        else          asm volatile("s_waitcnt vmcnt(8)" ::: "memory");
      } else {
        asm volatile("s_waitcnt vmcnt(0)" ::: "memory");
      }
      __builtin_amdgcn_s_barrier();    // all waves' set-ki DMAs complete
      __builtin_amdgcn_sched_barrier(0);

      const char* As = lds + cur * ABUF;
      const char* Bs = lds + NBUF * ABUF + cur * BBUF;

      #pragma unroll
      for (int half = 0; half < 2; ++half) {
        const int sz = swz ^ (half << 6);             // column byte offset
        f16x8 af[4], ad2[2], bg[4], bdv;
        #pragma unroll
        for (int fm = 0; fm < 4; ++fm)
          af[fm] = *(const f16x8*)(As + (64 * wr + 16 * fm + col16) * 128 + sz);
        #pragma unroll
        for (int d = 0; d < 2; ++d)
          ad2[d] = *(const f16x8*)(As + (32 * wave + 16 * d + col16) * 128 + sz);
        #pragma unroll
        for (int fn = 0; fn < 4; ++fn)
          bg[fn] = *(const f16x8*)(Bs + (32 * fn + wc * 16 + col16) * 128 + sz);
        bdv = *(const f16x8*)(Bs + (128 + col16) * 128 + sz);

        __builtin_amdgcn_s_setprio(1);               // T5: favor MFMA-entering wave
        #pragma unroll
        for (int fm = 0; fm < 4; ++fm)
          #pragma unroll
          for (int fn = 0; fn < 4; ++fn)
            accG[fm][fn] = __builtin_amdgcn_mfma_f32_16x16x32_f16(af[fm], bg[fn], accG[fm][fn], 0, 0, 0);
        accD[0] = __builtin_amdgcn_mfma_f32_16x16x32_f16(ad2[0], bdv, accD[0], 0, 0, 0);
        accD[1] = __builtin_amdgcn_mfma_f32_16x16x32_f16(ad2[1], bdv, accD[1], 0, 0, 0);
        __builtin_amdgcn_s_setprio(0);
      }

      __builtin_amdgcn_sched_barrier(0);
      __builtin_amdgcn_s_barrier();    // all waves done READING buf 'cur'
      __builtin_amdgcn_sched_barrier(0);

      if (ki < 13) issue_dma(cur, (ki + 3) * 64);     // refill same buffer
      cur = (cur == NBUF - 1) ? 0 : cur + 1;
    }

    // epilogue: gate math in registers; hold stays in VGPRs
    if (t < TS) {
      #pragma unroll
      for (int fm = 0; fm < 4; ++fm) {
        const int mbase = mt * 128 + 64 * wr + 16 * fm + quad * 4;
        #pragma unroll
        for (int ri = 0; ri < 4; ++ri) {
          const int m = mbase + ri;
          float rg = 1.f / (1.f + __expf(-(accG[fm][0][ri] + vbr)));
          float zg = 1.f / (1.f + __expf(-(accG[fm][1][ri] + vbz)));
          float nn = tanhf(accG[fm][2][ri] + vbi + rg * (accG[fm][3][ri] + vbh));
          float hnew = (1.f - zg) * nn + zg * hold[fm][ri];
          hold[fm][ri] = hnew;
          o16[(size_t)m * 1024 + j] = (_Float16)hnew;
        }
      }
    }
    if (t > 0 && col16 < 8) {          // decode of h_{t-1} -> out[:, t-1, :]
      const int oc = cb * 8 + col16;
      #pragma unroll
      for (int d = 0; d < 2; ++d) {
        const int mbase = mt * 128 + 32 * wave + 16 * d + quad * 4;
        #pragma unroll
        for (int ri = 0; ri < 4; ++ri) {
          const int m = mbase + ri;
          out[(size_t)m * (TS * OD) + (size_t)(t - 1) * OD + oc] = accD[d][ri] + vb;
        }
      }
    }

    // per-mt inter-block barrier (32 blocks share an mt group).
    // Release: syncthreads drains each thread's stores to L2 (vmcnt 0), then
    // tid0's threadfence wbl2-flushes this XCD's L2 to LLC. Acquire: after the
    // spin, threadfence invalidates L1/L2 so next step's DMA reads fresh h16.
    if (t < TS) {
      __syncthreads();
      if (tid == 0) {
        __threadfence();
        __hip_atomic_fetch_add(&ctr[mt * 32], 1u, __ATOMIC_RELEASE, __HIP_MEMORY_SCOPE_AGENT);
        while (__hip_atomic_load(&ctr[mt * 32], __ATOMIC_RELAXED, __HIP_MEMORY_SCOPE_AGENT)
               < 32u * (unsigned)(t + 1)) {
          __builtin_amdgcn_s_sleep(2);
        }
        __threadfence();
      }
      __syncthreads();
    }
  }
}

// ---------------- fallback step kernel (proven multi-launch path) ----------------
// Used only if the cooperative launch is rejected at enqueue time.
__global__ __launch_bounds__(256, 1) void step_kernel(
    const _Float16* __restrict__ Wws,
    const float* __restrict__ br, const float* __restrict__ bz,
    const float* __restrict__ bin_, const float* __restrict__ bhn,
    const float* __restrict__ bdec,
    const _Float16* __restrict__ h_in16, const float* __restrict__ h_in32,
    _Float16* __restrict__ h_out16, float* __restrict__ h_out32,
    float* __restrict__ out, int t)
{
  __shared__ __align__(16) char lds[2 * 16384 + 2 * 18432];

  const int tid = threadIdx.x;
  const int wave = tid >> 6, lane = tid & 63;
  const int mt = blockIdx.x >> 5, cb = blockIdx.x & 31;
  const int wr = wave >> 1, wc = wave & 1;
  const int col16 = lane & 15, quad = lane >> 4;

  const _Float16* __restrict__ slab  = Wws + (size_t)cb * (144 * 1024);
  const _Float16* __restrict__ Abase = h_in16 + (size_t)mt * (128 * 1024);

  int offs[4];
  #pragma unroll
  for (int jj = 0; jj < 4; ++jj) {
    int m = (wave * 4 + jj) * 64 + lane;
    int r = m >> 3, c = m & 7, g = c ^ (r & 7);
    offs[jj] = r * 1024 + g * 8;
  }
  int offE;
  { int m = 1024 + tid; int r = m >> 3, c = m & 7, g = c ^ (r & 7);
    offE = r * 1024 + g * 8; }

  const int swz = (quad ^ (col16 & 7)) << 4;

  f32x4 accG[4][4]; f32x4 accD[2];
  const f32x4 fzero = {0.f, 0.f, 0.f, 0.f};
  #pragma unroll
  for (int i = 0; i < 4; ++i)
    #pragma unroll
    for (int jj = 0; jj < 4; ++jj) accG[i][jj] = fzero;
  accD[0] = fzero; accD[1] = fzero;

  auto issue_dma = [&](int bsel, int kc) {
    char* Ab = lds + bsel * 16384;
    char* Bb = lds + 32768 + bsel * 18432;
    #pragma unroll
    for (int jj = 0; jj < 4; ++jj) {
      gl_lds16(Abase + offs[jj] + kc, Ab + (wave * 4 + jj) * 1024);
      gl_lds16(slab  + offs[jj] + kc, Bb + (wave * 4 + jj) * 1024);
    }
    if (wave < 2)
      gl_lds16(slab + offE + kc, Bb + 16384 + wave * 1024);
  };

  issue_dma(0, 0);
  __syncthreads();

  #pragma unroll 1
  for (int ki = 0; ki < 16; ++ki) {
    const int cur = ki & 1;
    if (ki < 15) issue_dma(cur ^ 1, (ki + 1) * 64);
    const char* As = lds + cur * 16384;
    const char* Bs = lds + 32768 + cur * 18432;

    #pragma unroll
    for (int half = 0; half < 2; ++half) {
      const int sz = swz ^ (half << 6);
      f16x8 af[4], ad2[2], bg[4], bdv;
      #pragma unroll
      for (int fm = 0; fm < 4; ++fm)
        af[fm] = *(const f16x8*)(As + (64 * wr + 16 * fm + col16) * 128 + sz);
      #pragma unroll
      for (int d = 0; d < 2; ++d)
        ad2[d] = *(const f16x8*)(As + (32 * wave + 16 * d + col16) * 128 + sz);
      #pragma unroll
      for (int fn = 0; fn < 4; ++fn)
        bg[fn] = *(const f16x8*)(Bs + (32 * fn + wc * 16 + col16) * 128 + sz);
      bdv = *(const f16x8*)(Bs + (128 + col16) * 128 + sz);

      #pragma unroll
      for (int fm = 0; fm < 4; ++fm)
        #pragma unroll
        for (int fn = 0; fn < 4; ++fn)
          accG[fm][fn] = __builtin_amdgcn_mfma_f32_16x16x32_f16(af[fm], bg[fn], accG[fm][fn], 0, 0, 0);
      accD[0] = __builtin_amdgcn_mfma_f32_16x16x32_f16(ad2[0], bdv, accD[0], 0, 0, 0);
      accD[1] = __builtin_amdgcn_mfma_f32_16x16x32_f16(ad2[1], bdv, accD[1], 0, 0, 0);
    }
    __syncthreads();
  }

  if (t < TS) {
    const int jj2 = cb * 32 + wc * 16 + col16;
    const float vbr = br[jj2], vbz = bz[jj2], vbi = bin_[jj2], vbh = bhn[jj2];
    #pragma unroll
    for (int fm = 0; fm < 4; ++fm) {
      const int mbase = mt * 128 + 64 * wr + 16 * fm + quad * 4;
      #pragma unroll
      for (int ri = 0; ri < 4; ++ri) {
        const int m = mbase + ri;
        float rg = 1.f / (1.f + __expf(-(accG[fm][0][ri] + vbr)));
        float zg = 1.f / (1.f + __expf(-(accG[fm][1][ri] + vbz)));
        float nn = tanhf(accG[fm][2][ri] + vbi + rg * (accG[fm][3][ri] + vbh));
        float hold = h_in32[(size_t)m * 1024 + jj2];
        float hnew = (1.f - zg) * nn + zg * hold;
        h_out32[(size_t)m * 1024 + jj2] = hnew;
        h_out16[(size_t)m * 1024 + jj2] = (_Float16)hnew;
      }
    }
  }
  if (t > 0 && col16 < 8) {
    const int oc = cb * 8 + col16;
    const float vb = bdec[oc];
    #pragma unroll
    for (int d = 0; d < 2; ++d) {
      const int mbase = mt * 128 + 32 * wave + 16 * d + quad * 4;
      #pragma unroll
      for (int ri = 0; ri < 4; ++ri) {
        const int m = mbase + ri;
        out[(size_t)m * (TS * OD) + (size_t)(t - 1) * OD + oc] = accD[d][ri] + vb;
      }
    }
  }
}

extern "C" void kernel_launch(void* const* d_in, const int* in_sizes, int n_in,
                              void* d_out, int out_size, void* d_ws, size_t ws_size,
                              hipStream_t stream) {
  const float* h0      = (const float*)d_in[0];   // [1,1024,1024]
  const float* Wih     = (const float*)d_in[1];   // [3072,256]
  const float* Whh     = (const float*)d_in[2];   // [3072,1024]
  const float* bih     = (const float*)d_in[3];   // [3072]
  const float* bhh     = (const float*)d_in[4];   // [3072]
  const float* Wdec    = (const float*)d_in[5];   // [256,1024]
  const float* bdec_in = (const float*)d_in[6];   // [256]
  float* out = (float*)d_out;                     // [1024,128,256] fp32

  char* ws = (char*)d_ws;
  _Float16* Wws = (_Float16*)ws;                         // 9,437,184 B
  float* br   = (float*)(ws + 9437184);
  float* bz   = (float*)(ws + 9437184 + 4096);
  float* bin_ = (float*)(ws + 9437184 + 8192);
  float* bhn  = (float*)(ws + 9437184 + 12288);
  float* bdec = (float*)(ws + 9437184 + 16384);
  _Float16* h16A = (_Float16*)(ws + 9461760);            // 2 MB
  _Float16* h16B = h16A + 1024 * 1024;                   // 2 MB
  unsigned int* ctr = (unsigned int*)(ws + 9461760 + 4194304);  // 1 KB
  float* h32A = (float*)(ws + 9461760 + 4194304 + 4096); // 4 MB (fallback only)
  float* h32B = h32A + 1024 * 1024;                      // 4 MB (fallback only)
  // total ws use ~21.9 MB

  prep_w<<<1152, 256, 0, stream>>>(Wih, Whh, Wdec, Wws);
  prep_bias<<<4, 256, 0, stream>>>(Wih, bih, bhh, bdec_in, br, bz, bin_, bhn, bdec, ctr);
  prep_h<<<4096, 256, 0, stream>>>(h0, h16A);

  void* kargs[] = {
    (void*)&Wws, (void*)&br, (void*)&bz, (void*)&bin_, (void*)&bhn, (void*)&bdec,
    (void*)&h0, (void*)&h16A, (void*)&h16B, (void*)&out, (void*)&ctr
  };
  hipError_t cerr = hipLaunchCooperativeKernel((void*)fused_gru, dim3(256), dim3(256),
                                               kargs, 0, stream);
  if (cerr != hipSuccess) {
    // Fallback: proven multi-launch path (uses fp32 h carry in memory).
    for (int t = 0; t <= TS; ++t) {
      const _Float16* in16 = (t & 1) ? h16B : h16A;
      const float*    in32 = (t == 0) ? h0 : ((t & 1) ? h32B : h32A);
      _Float16*       o16  = (t & 1) ? h16A : h16B;
      float*          o32  = (t & 1) ? h32A : h32B;
      step_kernel<<<256, 256, 0, stream>>>(Wws, br, bz, bin_, bhn, bdec,
                                           in16, in32, o16, o32, out, t);
    }
  }
}

// Round 3
// 2537.287 us; speedup vs baseline: 1.7025x; 1.7025x over previous
//
#include <hip/hip_runtime.h>
#include <cstdint>
#include <cstddef>

// RecurrentDecoder: 128 sequential GRU steps fused via x_t = h_t @ W_dec^T
// => gates = h @ W_eff^T (4096 gate cols + 256 decode cols), one GEMM/step.
// Round 9: persistent cooperative kernel, FENCELESS coherence.
//  R8 post-mortem: per-step __threadfence (buffer_wbl2+inv x256 blocks) caused
//  repeated XCD-L2 flash-invalidations -> B slabs refetched many times/step;
//  33us/step, MfmaUtil 12%. Fix: per-ACCESS coherence, no cache-wide ops:
//   - h16 stores: global_store_short sc0 sc1 (write-through to LLC)
//   - A-tile global_load_lds: aux=17 (sc0|sc1) -> bypass L1/L2, read LLC
//   - B-weight DMA: aux=0 -> stays hot in XCD L2 across all 128 steps
//   - inter-block barrier: relaxed agent atomics only (no threadfence);
//     release ordering via __syncthreads' implicit vmcnt(0) drain.
// 256 blocks = 8 mt x 32 cb; block tile [128 x 144], 4 waves (2x2).
// NBUF=3 DMA pipeline, counted s_waitcnt vmcnt(N) + raw s_barrier in K-loop.

#define HD 1024
#define OD 256
#define TS 128
#define NBUF 3
#define ABUF 16384
#define BBUF 18432

typedef _Float16 f16x8 __attribute__((ext_vector_type(8)));
typedef float f32x4 __attribute__((ext_vector_type(4)));

// aux: 0 = normal caching (L1+L2). 17 = sc0|sc1 = device-coherent: bypass
// stale L1/L2, serve from LLC (memory-side cache = coherence point).
template <int AUX>
__device__ __forceinline__ void gl_lds16(const void* g, void* l) {
  auto gp = reinterpret_cast<const __attribute__((address_space(1))) unsigned int*>(
      reinterpret_cast<uintptr_t>(g));
  auto lp = reinterpret_cast<__attribute__((address_space(3))) unsigned int*>(
      reinterpret_cast<uintptr_t>(l));
  __builtin_amdgcn_global_load_lds(gp, lp, 16, 0, AUX);
}

// device-scope write-through 2B store (reaches LLC before vmcnt retires)
__device__ __forceinline__ void st_h16_dev(_Float16* p, _Float16 v) {
  asm volatile("global_store_short %0, %1, off sc0 sc1"
               :: "v"(p), "v"(v) : "memory");
}

// ---------------- prep: build W_ws [32 cb][144 rows][1024 k] fp16 ----------------
__global__ __launch_bounds__(256) void prep_w(
    const float* __restrict__ Wih,   // [3072][256]
    const float* __restrict__ Whh,   // [3072][1024]
    const float* __restrict__ Wdec,  // [256][1024]
    _Float16* __restrict__ Wws)      // [32][144][1024]
{
  int blk = blockIdx.x, tid = threadIdx.x;
  int k0 = tid * 4;
  if (blk < 768) {                      // dot blocks: rows rr<96 (s in 0..2), 4 rows each
    int cbv[4], rrv[4], jg[4], jh[4];
    #pragma unroll
    for (int rsel = 0; rsel < 4; ++rsel) {
      int dj = blk * 4 + rsel;
      int cb = dj / 96, rr = dj % 96;
      int s = rr >> 5, wcol = (rr >> 4) & 1, p = rr & 15;
      int j = cb * 32 + wcol * 16 + p;
      cbv[rsel] = cb; rrv[rsel] = rr;
      jg[rsel] = s * 1024 + j;
      jh[rsel] = (s == 0) ? j : (s == 1 ? 1024 + j : -1);
    }
    float acc[4][4];
    #pragma unroll
    for (int a = 0; a < 4; ++a) { acc[a][0]=0.f; acc[a][1]=0.f; acc[a][2]=0.f; acc[a][3]=0.f; }
    for (int q = 0; q < 256; ++q) {
      float4 wd = *(const float4*)(Wdec + (size_t)q * 1024 + k0);
      #pragma unroll
      for (int a = 0; a < 4; ++a) {
        float w = Wih[(size_t)jg[a] * 256 + q];
        acc[a][0] += w * wd.x; acc[a][1] += w * wd.y;
        acc[a][2] += w * wd.z; acc[a][3] += w * wd.w;
      }
    }
    #pragma unroll
    for (int a = 0; a < 4; ++a) {
      if (jh[a] >= 0) {
        const float* wh = Whh + (size_t)jh[a] * 1024 + k0;
        acc[a][0] += wh[0]; acc[a][1] += wh[1];
        acc[a][2] += wh[2]; acc[a][3] += wh[3];
      }
      _Float16* dst = Wws + ((size_t)cbv[a] * 144 + rrv[a]) * 1024 + k0;
      dst[0] = (_Float16)acc[a][0]; dst[1] = (_Float16)acc[a][1];
      dst[2] = (_Float16)acc[a][2]; dst[3] = (_Float16)acc[a][3];
    }
  } else {                              // copy blocks: rows rr in 96..143
    #pragma unroll
    for (int rsel = 0; rsel < 4; ++rsel) {
      int cr = (blk - 768) * 4 + rsel;
      int cb = cr / 48, rr = 96 + cr % 48;
      _Float16* dst = Wws + ((size_t)cb * 144 + rr) * 1024 + k0;
      if (rr < 128) {                   // s=3: Whh[2048+j]
        int j = cb * 32 + ((rr >> 4) & 1) * 16 + (rr & 15);
        const float* src = Whh + (size_t)(2048 + j) * 1024 + k0;
        dst[0] = (_Float16)src[0]; dst[1] = (_Float16)src[1];
        dst[2] = (_Float16)src[2]; dst[3] = (_Float16)src[3];
      } else if (rr < 136) {
        const float* src = Wdec + (size_t)(cb * 8 + rr - 128) * 1024 + k0;
        dst[0] = (_Float16)src[0]; dst[1] = (_Float16)src[1];
        dst[2] = (_Float16)src[2]; dst[3] = (_Float16)src[3];
      } else {
        dst[0] = (_Float16)0.f; dst[1] = (_Float16)0.f;
        dst[2] = (_Float16)0.f; dst[3] = (_Float16)0.f;
      }
    }
  }
}

__global__ __launch_bounds__(256) void prep_bias(
    const float* __restrict__ Wih,
    const float* __restrict__ bih, const float* __restrict__ bhh,
    const float* __restrict__ bdec_in,
    float* __restrict__ br, float* __restrict__ bz, float* __restrict__ bin_,
    float* __restrict__ bhn, float* __restrict__ bdec,
    unsigned int* __restrict__ ctr)
{
  int j = blockIdx.x * 256 + threadIdx.x;   // grid 4 -> j < 1024
  if (blockIdx.x == 0) ctr[threadIdx.x] = 0u;   // reset per-mt barrier counters
  float bc0 = 0.f, bc1 = 0.f, bc2 = 0.f;
  for (int q = 0; q < 256; ++q) {
    float bd = bdec_in[q];
    bc0 += Wih[(size_t)j * 256 + q] * bd;
    bc1 += Wih[(size_t)(1024 + j) * 256 + q] * bd;
    bc2 += Wih[(size_t)(2048 + j) * 256 + q] * bd;
  }
  br[j]  = bih[j]        + bhh[j]        + bc0;
  bz[j]  = bih[1024 + j] + bhh[1024 + j] + bc1;
  bin_[j]= bih[2048 + j] + bc2;
  bhn[j] = bhh[2048 + j];
  if (j < 256) bdec[j] = bdec_in[j];
}

__global__ __launch_bounds__(256) void prep_h(
    const float* __restrict__ h0, _Float16* __restrict__ h16)
{
  int i = blockIdx.x * 256 + threadIdx.x;
  h16[i] = (_Float16)h0[i];
}

// ---------------- persistent fused kernel (cooperative) ----------------
// grid 256 = mt(8)*32 + cb(32); 256 thr = 4 waves (2x2 over [128x128] gates).
// LDS: 3 A bufs (16384 B) then 3 B bufs (18432 B). Per buffer: [row][8 kgroups
// of 16B], row stride 128 B; kgroup XOR-swizzled by (row&7), folded into the
// DMA's per-lane GLOBAL address so LDS destinations stay lane-linear.
// K-loop: counted vmcnt (steady state 2 sets in flight; per-wave set size
// L = 9 (waves 0,1) / 8 (waves 2,3)); raw s_barrier, never vmcnt(0) mid-loop.
// NOTE on vmcnt accounting: wave0's tid0 release-atomic from the previous
// step may still be outstanding at prologue time; it is the OLDEST op, so
// waiting vmcnt(N) still guarantees the needed DMA sets are complete.
__global__ __launch_bounds__(256, 1) void fused_gru(
    const _Float16* __restrict__ Wws,
    const float* __restrict__ br, const float* __restrict__ bz,
    const float* __restrict__ bin_, const float* __restrict__ bhn,
    const float* __restrict__ bdec,
    const float* __restrict__ h0,
    _Float16* __restrict__ h16A, _Float16* __restrict__ h16B,
    float* __restrict__ out,
    unsigned int* __restrict__ ctr)
{
  __shared__ __align__(16) char lds[NBUF * (ABUF + BBUF)];   // 104448 B

  const int tid = threadIdx.x;
  const int wave = tid >> 6, lane = tid & 63;
  const int mt = blockIdx.x >> 5, cb = blockIdx.x & 31;
  const int wr = wave >> 1, wc = wave & 1;
  const int col16 = lane & 15, quad = lane >> 4;

  const _Float16* __restrict__ slab = Wws + (size_t)cb * (144 * 1024);

  // DMA chunk geometry: chunk m (16 B) covers row r=m>>3, lds-kgroup c=m&7;
  // global kgroup g = c ^ (r&7) (swizzle). Wave w, issue j covers chunks
  // (w*4+j)*64 + lane. Extra B chunks 1024+tid (tid<128) cover rows 128..143.
  int offs[4];
  #pragma unroll
  for (int jj = 0; jj < 4; ++jj) {
    int m = (wave * 4 + jj) * 64 + lane;
    int r = m >> 3, c = m & 7, g = c ^ (r & 7);
    offs[jj] = r * 1024 + g * 8;       // element (half) offset
  }
  int offE;
  { int m = 1024 + tid; int r = m >> 3, c = m & 7, g = c ^ (r & 7);
    offE = r * 1024 + g * 8; }         // valid when tid < 128

  const int swz = (quad ^ (col16 & 7)) << 4;   // ds_read swizzled col base; K-hi = ^64 B

  // loop-invariant epilogue constants (loaded once)
  const int j = cb * 32 + wc * 16 + col16;     // gate col 0..1023
  const float vbr = br[j], vbz = bz[j], vbi = bin_[j], vbh = bhn[j];
  const float vb = bdec[cb * 8 + (col16 & 7)]; // used only when col16 < 8

  // fp32 hold carried in registers across all 128 steps (C/D layout:
  // n = lane&15, m = quad*4 + reg). Seeded from h0.
  float hold[4][4];
  #pragma unroll
  for (int fm = 0; fm < 4; ++fm) {
    const int mbase = mt * 128 + 64 * wr + 16 * fm + quad * 4;
    #pragma unroll
    for (int ri = 0; ri < 4; ++ri)
      hold[fm][ri] = h0[(size_t)(mbase + ri) * 1024 + j];
  }
  // drain preloads so in-loop vmcnt accounting is exact
  asm volatile("s_waitcnt vmcnt(0)" ::: "memory");

  const f32x4 fzero = {0.f, 0.f, 0.f, 0.f};

  #pragma unroll 1
  for (int t = 0; t <= TS; ++t) {      // t=TS: decode-only pass for out[:,127,:]
    const _Float16* __restrict__ Abase =
        ((t & 1) ? h16B : h16A) + (size_t)mt * (128 * 1024);
    _Float16* __restrict__ o16 = (t & 1) ? h16A : h16B;

    f32x4 accG[4][4]; f32x4 accD[2];
    #pragma unroll
    for (int i = 0; i < 4; ++i)
      #pragma unroll
      for (int jj = 0; jj < 4; ++jj) accG[i][jj] = fzero;
    accD[0] = fzero; accD[1] = fzero;

    // A (h16): device-coherent loads from LLC (aux=17); B (weights): normal
    // cached loads -> hot in XCD L2 all 128 steps (never invalidated).
    auto issue_dma = [&](int bsel, int kc) {
      char* Ab = lds + bsel * ABUF;
      char* Bb = lds + NBUF * ABUF + bsel * BBUF;
      #pragma unroll
      for (int jj = 0; jj < 4; ++jj) {
        gl_lds16<17>(Abase + offs[jj] + kc, Ab + (wave * 4 + jj) * 1024);
        gl_lds16<0>(slab  + offs[jj] + kc, Bb + (wave * 4 + jj) * 1024);
      }
      if (wave < 2)
        gl_lds16<0>(slab + offE + kc, Bb + 16384 + wave * 1024);
    };

    // prologue: 3 K-sets in flight
    issue_dma(0, 0);
    issue_dma(1, 64);
    issue_dma(2, 128);

    int cur = 0;
    #pragma unroll 1
    for (int ki = 0; ki < 16; ++ki) {
      // counted wait: need set ki complete; allow 2 newer sets in flight.
      // Sets issued: 3 + min(ki,13). ki<=13 -> wait 2L; ki==14 -> L; ki==15 -> 0.
      __builtin_amdgcn_sched_barrier(0);
      if (ki < 14) {
        if (wave < 2) asm volatile("s_waitcnt vmcnt(18)" ::: "memory");
        else          asm volatile("s_waitcnt vmcnt(16)" ::: "memory");
      } else if (ki == 14) {
        if (wave < 2) asm volatile("s_waitcnt vmcnt(9)" ::: "memory");
        else          asm volatile("s_waitcnt vmcnt(8)" ::: "memory");
      } else {
        asm volatile("s_waitcnt vmcnt(0)" ::: "memory");
      }
      __builtin_amdgcn_s_barrier();    // all waves' set-ki DMAs complete
      __builtin_amdgcn_sched_barrier(0);

      const char* As = lds + cur * ABUF;
      const char* Bs = lds + NBUF * ABUF + cur * BBUF;

      #pragma unroll
      for (int half = 0; half < 2; ++half) {
        const int sz = swz ^ (half << 6);             // column byte offset
        f16x8 af[4], ad2[2], bg[4], bdv;
        #pragma unroll
        for (int fm = 0; fm < 4; ++fm)
          af[fm] = *(const f16x8*)(As + (64 * wr + 16 * fm + col16) * 128 + sz);
        #pragma unroll
        for (int d = 0; d < 2; ++d)
          ad2[d] = *(const f16x8*)(As + (32 * wave + 16 * d + col16) * 128 + sz);
        #pragma unroll
        for (int fn = 0; fn < 4; ++fn)
          bg[fn] = *(const f16x8*)(Bs + (32 * fn + wc * 16 + col16) * 128 + sz);
        bdv = *(const f16x8*)(Bs + (128 + col16) * 128 + sz);

        __builtin_amdgcn_s_setprio(1);               // T5: favor MFMA-entering wave
        #pragma unroll
        for (int fm = 0; fm < 4; ++fm)
          #pragma unroll
          for (int fn = 0; fn < 4; ++fn)
            accG[fm][fn] = __builtin_amdgcn_mfma_f32_16x16x32_f16(af[fm], bg[fn], accG[fm][fn], 0, 0, 0);
        accD[0] = __builtin_amdgcn_mfma_f32_16x16x32_f16(ad2[0], bdv, accD[0], 0, 0, 0);
        accD[1] = __builtin_amdgcn_mfma_f32_16x16x32_f16(ad2[1], bdv, accD[1], 0, 0, 0);
        __builtin_amdgcn_s_setprio(0);
      }

      __builtin_amdgcn_sched_barrier(0);
      __builtin_amdgcn_s_barrier();    // all waves done READING buf 'cur'
      __builtin_amdgcn_sched_barrier(0);

      if (ki < 13) issue_dma(cur, (ki + 3) * 64);     // refill same buffer
      cur = (cur == NBUF - 1) ? 0 : cur + 1;
    }

    // epilogue: gate math in registers; hold stays in VGPRs; h16 stores are
    // device write-through (sc0 sc1) so no cache flush is ever needed.
    if (t < TS) {
      #pragma unroll
      for (int fm = 0; fm < 4; ++fm) {
        const int mbase = mt * 128 + 64 * wr + 16 * fm + quad * 4;
        #pragma unroll
        for (int ri = 0; ri < 4; ++ri) {
          const int m = mbase + ri;
          float rg = 1.f / (1.f + __expf(-(accG[fm][0][ri] + vbr)));
          float zg = 1.f / (1.f + __expf(-(accG[fm][1][ri] + vbz)));
          float nn = tanhf(accG[fm][2][ri] + vbi + rg * (accG[fm][3][ri] + vbh));
          float hnew = (1.f - zg) * nn + zg * hold[fm][ri];
          hold[fm][ri] = hnew;
          st_h16_dev(o16 + (size_t)m * 1024 + j, (_Float16)hnew);
        }
      }
    }
    if (t > 0 && col16 < 8) {          // decode of h_{t-1} -> out[:, t-1, :]
      const int oc = cb * 8 + col16;
      #pragma unroll
      for (int d = 0; d < 2; ++d) {
        const int mbase = mt * 128 + 32 * wave + 16 * d + quad * 4;
        #pragma unroll
        for (int ri = 0; ri < 4; ++ri) {
          const int m = mbase + ri;
          out[(size_t)m * (TS * OD) + (size_t)(t - 1) * OD + oc] = accD[d][ri] + vb;
        }
      }
    }

    // per-mt inter-block barrier (32 blocks share an mt group), FENCELESS.
    // Release: __syncthreads' implicit vmcnt(0) drains every thread's sc1
    // write-through stores (visible at LLC), then tid0's relaxed agent atomic.
    // Acquire: spin on relaxed agent load (LLC); subsequent A-loads are
    // device-coherent (aux=17), so no cache invalidation is required.
    if (t < TS) {
      __syncthreads();
      if (tid == 0) {
        __hip_atomic_fetch_add(&ctr[mt * 32], 1u, __ATOMIC_RELAXED, __HIP_MEMORY_SCOPE_AGENT);
        while (__hip_atomic_load(&ctr[mt * 32], __ATOMIC_RELAXED, __HIP_MEMORY_SCOPE_AGENT)
               < 32u * (unsigned)(t + 1)) {
          __builtin_amdgcn_s_sleep(1);
        }
      }
      __syncthreads();
    }
  }
}

// ---------------- fallback step kernel (proven multi-launch path) ----------------
// Used only if the cooperative launch is rejected at enqueue time.
__global__ __launch_bounds__(256, 1) void step_kernel(
    const _Float16* __restrict__ Wws,
    const float* __restrict__ br, const float* __restrict__ bz,
    const float* __restrict__ bin_, const float* __restrict__ bhn,
    const float* __restrict__ bdec,
    const _Float16* __restrict__ h_in16, const float* __restrict__ h_in32,
    _Float16* __restrict__ h_out16, float* __restrict__ h_out32,
    float* __restrict__ out, int t)
{
  __shared__ __align__(16) char lds[2 * 16384 + 2 * 18432];

  const int tid = threadIdx.x;
  const int wave = tid >> 6, lane = tid & 63;
  const int mt = blockIdx.x >> 5, cb = blockIdx.x & 31;
  const int wr = wave >> 1, wc = wave & 1;
  const int col16 = lane & 15, quad = lane >> 4;

  const _Float16* __restrict__ slab  = Wws + (size_t)cb * (144 * 1024);
  const _Float16* __restrict__ Abase = h_in16 + (size_t)mt * (128 * 1024);

  int offs[4];
  #pragma unroll
  for (int jj = 0; jj < 4; ++jj) {
    int m = (wave * 4 + jj) * 64 + lane;
    int r = m >> 3, c = m & 7, g = c ^ (r & 7);
    offs[jj] = r * 1024 + g * 8;
  }
  int offE;
  { int m = 1024 + tid; int r = m >> 3, c = m & 7, g = c ^ (r & 7);
    offE = r * 1024 + g * 8; }

  const int swz = (quad ^ (col16 & 7)) << 4;

  f32x4 accG[4][4]; f32x4 accD[2];
  const f32x4 fzero = {0.f, 0.f, 0.f, 0.f};
  #pragma unroll
  for (int i = 0; i < 4; ++i)
    #pragma unroll
    for (int jj = 0; jj < 4; ++jj) accG[i][jj] = fzero;
  accD[0] = fzero; accD[1] = fzero;

  auto issue_dma = [&](int bsel, int kc) {
    char* Ab = lds + bsel * 16384;
    char* Bb = lds + 32768 + bsel * 18432;
    #pragma unroll
    for (int jj = 0; jj < 4; ++jj) {
      gl_lds16<0>(Abase + offs[jj] + kc, Ab + (wave * 4 + jj) * 1024);
      gl_lds16<0>(slab  + offs[jj] + kc, Bb + (wave * 4 + jj) * 1024);
    }
    if (wave < 2)
      gl_lds16<0>(slab + offE + kc, Bb + 16384 + wave * 1024);
  };

  issue_dma(0, 0);
  __syncthreads();

  #pragma unroll 1
  for (int ki = 0; ki < 16; ++ki) {
    const int cur = ki & 1;
    if (ki < 15) issue_dma(cur ^ 1, (ki + 1) * 64);
    const char* As = lds + cur * 16384;
    const char* Bs = lds + 32768 + cur * 18432;

    #pragma unroll
    for (int half = 0; half < 2; ++half) {
      const int sz = swz ^ (half << 6);
      f16x8 af[4], ad2[2], bg[4], bdv;
      #pragma unroll
      for (int fm = 0; fm < 4; ++fm)
        af[fm] = *(const f16x8*)(As + (64 * wr + 16 * fm + col16) * 128 + sz);
      #pragma unroll
      for (int d = 0; d < 2; ++d)
        ad2[d] = *(const f16x8*)(As + (32 * wave + 16 * d + col16) * 128 + sz);
      #pragma unroll
      for (int fn = 0; fn < 4; ++fn)
        bg[fn] = *(const f16x8*)(Bs + (32 * fn + wc * 16 + col16) * 128 + sz);
      bdv = *(const f16x8*)(Bs + (128 + col16) * 128 + sz);

      #pragma unroll
      for (int fm = 0; fm < 4; ++fm)
        #pragma unroll
        for (int fn = 0; fn < 4; ++fn)
          accG[fm][fn] = __builtin_amdgcn_mfma_f32_16x16x32_f16(af[fm], bg[fn], accG[fm][fn], 0, 0, 0);
      accD[0] = __builtin_amdgcn_mfma_f32_16x16x32_f16(ad2[0], bdv, accD[0], 0, 0, 0);
      accD[1] = __builtin_amdgcn_mfma_f32_16x16x32_f16(ad2[1], bdv, accD[1], 0, 0, 0);
    }
    __syncthreads();
  }

  if (t < TS) {
    const int jj2 = cb * 32 + wc * 16 + col16;
    const float vbr = br[jj2], vbz = bz[jj2], vbi = bin_[jj2], vbh = bhn[jj2];
    #pragma unroll
    for (int fm = 0; fm < 4; ++fm) {
      const int mbase = mt * 128 + 64 * wr + 16 * fm + quad * 4;
      #pragma unroll
      for (int ri = 0; ri < 4; ++ri) {
        const int m = mbase + ri;
        float rg = 1.f / (1.f + __expf(-(accG[fm][0][ri] + vbr)));
        float zg = 1.f / (1.f + __expf(-(accG[fm][1][ri] + vbz)));
        float nn = tanhf(accG[fm][2][ri] + vbi + rg * (accG[fm][3][ri] + vbh));
        float hold = h_in32[(size_t)m * 1024 + jj2];
        float hnew = (1.f - zg) * nn + zg * hold;
        h_out32[(size_t)m * 1024 + jj2] = hnew;
        h_out16[(size_t)m * 1024 + jj2] = (_Float16)hnew;
      }
    }
  }
  if (t > 0 && col16 < 8) {
    const int oc = cb * 8 + col16;
    const float vb = bdec[oc];
    #pragma unroll
    for (int d = 0; d < 2; ++d) {
      const int mbase = mt * 128 + 32 * wave + 16 * d + quad * 4;
      #pragma unroll
      for (int ri = 0; ri < 4; ++ri) {
        const int m = mbase + ri;
        out[(size_t)m * (TS * OD) + (size_t)(t - 1) * OD + oc] = accD[d][ri] + vb;
      }
    }
  }
}

extern "C" void kernel_launch(void* const* d_in, const int* in_sizes, int n_in,
                              void* d_out, int out_size, void* d_ws, size_t ws_size,
                              hipStream_t stream) {
  const float* h0      = (const float*)d_in[0];   // [1,1024,1024]
  const float* Wih     = (const float*)d_in[1];   // [3072,256]
  const float* Whh     = (const float*)d_in[2];   // [3072,1024]
  const float* bih     = (const float*)d_in[3];   // [3072]
  const float* bhh     = (const float*)d_in[4];   // [3072]
  const float* Wdec    = (const float*)d_in[5];   // [256,1024]
  const float* bdec_in = (const float*)d_in[6];   // [256]
  float* out = (float*)d_out;                     // [1024,128,256] fp32

  char* ws = (char*)d_ws;
  _Float16* Wws = (_Float16*)ws;                         // 9,437,184 B
  float* br   = (float*)(ws + 9437184);
  float* bz   = (float*)(ws + 9437184 + 4096);
  float* bin_ = (float*)(ws + 9437184 + 8192);
  float* bhn  = (float*)(ws + 9437184 + 12288);
  float* bdec = (float*)(ws + 9437184 + 16384);
  _Float16* h16A = (_Float16*)(ws + 9461760);            // 2 MB
  _Float16* h16B = h16A + 1024 * 1024;                   // 2 MB
  unsigned int* ctr = (unsigned int*)(ws + 9461760 + 4194304);  // 1 KB
  float* h32A = (float*)(ws + 9461760 + 4194304 + 4096); // 4 MB (fallback only)
  float* h32B = h32A + 1024 * 1024;                      // 4 MB (fallback only)
  // total ws use ~21.9 MB

  prep_w<<<1152, 256, 0, stream>>>(Wih, Whh, Wdec, Wws);
  prep_bias<<<4, 256, 0, stream>>>(Wih, bih, bhh, bdec_in, br, bz, bin_, bhn, bdec, ctr);
  prep_h<<<4096, 256, 0, stream>>>(h0, h16A);

  void* kargs[] = {
    (void*)&Wws, (void*)&br, (void*)&bz, (void*)&bin_, (void*)&bhn, (void*)&bdec,
    (void*)&h0, (void*)&h16A, (void*)&h16B, (void*)&out, (void*)&ctr
  };
  hipError_t cerr = hipLaunchCooperativeKernel((void*)fused_gru, dim3(256), dim3(256),
                                               kargs, 0, stream);
  if (cerr != hipSuccess) {
    // Fallback: proven multi-launch path (uses fp32 h carry in memory).
    for (int t = 0; t <= TS; ++t) {
      const _Float16* in16 = (t & 1) ? h16B : h16A;
      const float*    in32 = (t == 0) ? h0 : ((t & 1) ? h32B : h32A);
      _Float16*       o16  = (t & 1) ? h16A : h16B;
      float*          o32  = (t & 1) ? h32A : h32B;
      step_kernel<<<256, 256, 0, stream>>>(Wws, br, bz, bin_, bhn, bdec,
                                           in16, in32, o16, o32, out, t);
    }
  }
}